// Round 4
// baseline (407.451 us; speedup 1.0000x reference)
//
#include <hip/hip_runtime.h>

#define DD 128
#define CHUNK 6144   // edges per block in S1/S3
#define NBMAX 512    // max buckets (N <= 65536)
#define SCAP 8192    // per-bucket LDS staging capacity

typedef __attribute__((ext_vector_type(8))) short bf16x8;
typedef __attribute__((ext_vector_type(4))) float f32x4;

// ---------- bf16 helpers ----------
__device__ __forceinline__ unsigned bf16rne(float f) {
  unsigned u = __float_as_uint(f);
  return (u + 0x7FFFu + ((u >> 16) & 1u)) >> 16;
}
__device__ __forceinline__ unsigned packbf(float lo, float hi) {
  return bf16rne(lo) | (bf16rne(hi) << 16);
}
__device__ __forceinline__ float bflo(unsigned v) { return __uint_as_float(v << 16); }
__device__ __forceinline__ float bfhi(unsigned v) { return __uint_as_float(v & 0xFFFF0000u); }

// ---------- inclusive block scan over LDS array (256 threads, nb <= 512) ----------
__device__ void block_scan_incl(int* cnt, int* inc, int nb, int tid) {
  for (int i = tid; i < nb; i += 256) inc[i] = cnt[i];
  __syncthreads();
  for (int d = 1; d < nb; d <<= 1) {
    int i0 = tid, i1 = tid + 256;
    int v0 = 0, v1 = 0;
    if (i0 < nb && i0 >= d) v0 = inc[i0 - d];
    if (i1 < nb && i1 >= d) v1 = inc[i1 - d];
    __syncthreads();
    if (i0 < nb) inc[i0] += v0;
    if (i1 < nb) inc[i1] += v1;
    __syncthreads();
  }
}

// ---------- S1: bucket histogram (bucket = dst >> 7) ----------
__global__ __launch_bounds__(256) void s1_hist(const int* __restrict__ dst,
                                               int* __restrict__ bucketCount, int e) {
  __shared__ int h[NBMAX];
  int tid = threadIdx.x;
  for (int i = tid; i < NBMAX; i += 256) h[i] = 0;
  __syncthreads();
  int i0 = blockIdx.x * CHUNK;
  int i1 = min(i0 + CHUNK, e);
  for (int i = i0 + tid; i < i1; i += 256) atomicAdd(&h[dst[i] >> 7], 1);
  __syncthreads();
  for (int i = tid; i < NBMAX; i += 256)
    if (h[i]) atomicAdd(&bucketCount[i], h[i]);
}

// ---------- S2: scan bucket counts ----------
__global__ __launch_bounds__(256) void s2_scan(const int* __restrict__ bucketCount,
                                               int* __restrict__ bucketOff,
                                               int* __restrict__ gCursor,
                                               int* __restrict__ rs, int nb, int n, int e) {
  __shared__ int cnt[NBMAX], inc[NBMAX];
  int tid = threadIdx.x;
  for (int i = tid; i < nb; i += 256) cnt[i] = bucketCount[i];
  __syncthreads();
  block_scan_incl(cnt, inc, nb, tid);
  for (int i = tid; i < nb; i += 256) {
    int off = inc[i] - cnt[i];
    bucketOff[i] = off;
    gCursor[i] = off;
  }
  if (tid == 0) { bucketOff[nb] = e; rs[n] = e; }
}

// ---------- S3: block-local grouping + coalesced bucket scatter ----------
__global__ __launch_bounds__(256) void s3_scatter(const int* __restrict__ src,
                                                  const int* __restrict__ dst,
                                                  int* __restrict__ gCursor,
                                                  unsigned int* __restrict__ bucketed,
                                                  int e, int nb) {
  __shared__ int cnt[NBMAX], inc[NBMAX], base[NBMAX], cur[NBMAX];
  __shared__ unsigned int pairs[CHUNK];
  int tid = threadIdx.x;
  for (int i = tid; i < nb; i += 256) cnt[i] = 0;
  __syncthreads();
  int i0 = blockIdx.x * CHUNK;
  int i1 = min(i0 + CHUNK, e);
  for (int i = i0 + tid; i < i1; i += 256) atomicAdd(&cnt[dst[i] >> 7], 1);
  __syncthreads();
  block_scan_incl(cnt, inc, nb, tid);
  for (int b = tid; b < nb; b += 256) {
    int c = cnt[b];
    base[b] = c ? atomicAdd(&gCursor[b], c) : 0;
    cur[b] = inc[b] - c;
  }
  __syncthreads();
  for (int i = i0 + tid; i < i1; i += 256) {
    int d = dst[i];
    int p = atomicAdd(&cur[d >> 7], 1);
    pairs[p] = (unsigned)d | ((unsigned)src[i] << 16);
  }
  __syncthreads();
  int m = i1 - i0;
  for (int i = tid; i < m; i += 256) {
    unsigned w = pairs[i];
    int b = (int)(w & 0xFFFFu) >> 7;
    bucketed[base[b] + (i - (inc[b] - cnt[b]))] = w;
  }
}

// ---------- S4: per-bucket node-level fill; emits rs[] and u16 ssrc ----------
__global__ __launch_bounds__(256) void s4_fill(const unsigned int* __restrict__ bucketed,
                                               const int* __restrict__ bucketOff,
                                               int* __restrict__ rs,
                                               unsigned short* __restrict__ ssrc, int n) {
  __shared__ int cnt[128], inc[128], cur[128];
  __shared__ unsigned short outb[SCAP];
  int b = blockIdx.x;
  int bo = bucketOff[b], b1 = bucketOff[b + 1];
  int len = b1 - bo;
  int tid = threadIdx.x;
  int n0 = b << 7;
  if (tid < 128) cnt[tid] = 0;
  __syncthreads();
  for (int i = tid; i < len; i += 256) atomicAdd(&cnt[bucketed[bo + i] & 127], 1);
  __syncthreads();
  if (tid < 128) inc[tid] = cnt[tid];
  __syncthreads();
  for (int d = 1; d < 128; d <<= 1) {
    int v = 0;
    if (tid < 128 && tid >= d) v = inc[tid - d];
    __syncthreads();
    if (tid < 128) inc[tid] += v;
    __syncthreads();
  }
  if (tid < 128) {
    int off = inc[tid] - cnt[tid];
    cur[tid] = off;
    int node = n0 + tid;
    if (node < n) rs[node] = bo + off;
  }
  __syncthreads();
  if (len <= SCAP) {
    for (int i = tid; i < len; i += 256) {
      unsigned w = bucketed[bo + i];
      int p = atomicAdd(&cur[w & 127], 1);
      outb[p] = (unsigned short)(w >> 16);
    }
    __syncthreads();
    for (int i = tid; i < len; i += 256) ssrc[bo + i] = outb[i];
  } else {
    for (int i = tid; i < len; i += 256) {
      unsigned w = bucketed[bo + i];
      int p = atomicAdd(&cur[w & 127], 1);
      ssrc[bo + p] = (unsigned short)(w >> 16);
    }
  }
}

// ---------- conv: f32 -> packed bf16x2 ----------
__global__ __launch_bounds__(256) void conv_bf16(const float* __restrict__ x,
                                                 unsigned int* __restrict__ hb, int n64) {
  int i = blockIdx.x * 256 + threadIdx.x;
  if (i < n64) {
    float2 v = ((const float2*)x)[i];
    hb[i] = packbf(v.x, v.y);
  }
}

// ---------- W prep: split W into (hi, lo) bf16, transposed [col][k] ----------
__global__ __launch_bounds__(256) void prep_w(const float* __restrict__ W1,
                                              const float* __restrict__ W2,
                                              short* __restrict__ wt) {
  int idx = blockIdx.x * 256 + threadIdx.x;  // 3*2*16384
  if (idx >= 3 * 2 * 16384) return;
  int lm = idx >> 14;      // layer*2 + mat
  int e = idx & 16383;
  int k = e >> 7;
  int col = e & 127;
  int layer = lm >> 1, mat = lm & 1;
  const float* W = mat ? W2 : W1;
  float w = W[layer * 16384 + k * 128 + col];
  unsigned short h = (unsigned short)bf16rne(w);
  float hv = __uint_as_float((unsigned)h << 16);
  unsigned short lo = (unsigned short)bf16rne(w - hv);
  size_t base = (size_t)lm * 2 * 16384;
  wt[base + col * 128 + k] = (short)h;
  wt[base + 16384 + col * 128 + k] = (short)lo;
}

// ---------- chunked aggregation: 64 bf16 cols per pass, 2 nodes per wave ----------
// chunk in {0,1}: cols [chunk*64, chunk*64+64) = uints [chunk*32, chunk*32+32)
__global__ __launch_bounds__(256) void gather_chunk(const unsigned int* __restrict__ hb,
                                                    const int* __restrict__ rs,
                                                    const unsigned short* __restrict__ ssrc,
                                                    unsigned int* __restrict__ zb,
                                                    int n, int chunk) {
  int node = blockIdx.x * 8 + (threadIdx.x >> 5);  // 8 half-waves per block
  if (node >= n) return;
  int lane = threadIdx.x & 31;
  int cbase = chunk * 32 + lane;
  int s0 = rs[node], s1 = rs[node + 1];
  unsigned v = hb[(size_t)node * 64 + cbase];
  float ax = bflo(v), ay = bfhi(v);
  int t = s0;
  for (; t + 3 < s1; t += 4) {
    int sa = ssrc[t], sb = ssrc[t + 1], sc = ssrc[t + 2], sd = ssrc[t + 3];
    unsigned va = hb[(size_t)sa * 64 + cbase];
    unsigned vb = hb[(size_t)sb * 64 + cbase];
    unsigned vc = hb[(size_t)sc * 64 + cbase];
    unsigned vd = hb[(size_t)sd * 64 + cbase];
    ax += bflo(va) + bflo(vb) + bflo(vc) + bflo(vd);
    ay += bfhi(va) + bfhi(vb) + bfhi(vc) + bfhi(vd);
  }
  for (; t < s1; ++t) {
    unsigned vv = hb[(size_t)ssrc[t] * 64 + cbase];
    ax += bflo(vv);
    ay += bfhi(vv);
  }
  zb[(size_t)node * 64 + cbase] = packbf(ax, ay);
}

// ---------- MFMA MLP: hout = relu(z@W1+b1)@W2+b2 ----------
__global__ __launch_bounds__(128, 2) void mlp_mfma(
    const unsigned int* __restrict__ zb,
    const short* __restrict__ Wt1, const short* __restrict__ Wt2,
    const float* __restrict__ b1, const float* __restrict__ b2,
    float* __restrict__ fout, unsigned short* __restrict__ hbout, int n) {
  __shared__ char hsb[64 * 256];  // 16KB swizzled bf16 h-tile
  int tid = threadIdx.x;
  int w = tid >> 6, lane = tid & 63;
  int lr = lane & 15, hi = lane >> 4;
  int node0 = blockIdx.x * 64;

  bf16x8 a[2][4];
#pragma unroll
  for (int t = 0; t < 2; ++t) {
    int row = node0 + w * 32 + t * 16 + lr;
    row = min(row, n - 1);
    const char* rp = (const char*)(zb + (size_t)row * 64);
#pragma unroll
    for (int ks = 0; ks < 4; ++ks)
      a[t][ks] = *(const bf16x8*)(rp + ks * 64 + hi * 16);
  }

  f32x4 acc[2][8];
#pragma unroll
  for (int ct = 0; ct < 8; ++ct) {
    float bb = b1[ct * 16 + lr];
    acc[0][ct] = (f32x4){bb, bb, bb, bb};
    acc[1][ct] = acc[0][ct];
  }

  const char* wbase1 = (const char*)Wt1 + ((size_t)lr * 128 + hi * 8) * 2;
#pragma unroll
  for (int p = 0; p < 2; ++p) {
    const char* wp = wbase1 + p * 32768;
#pragma unroll
    for (int ct = 0; ct < 8; ++ct) {
#pragma unroll
      for (int ks = 0; ks < 4; ++ks) {
        bf16x8 b = *(const bf16x8*)(wp + ct * 4096 + ks * 64);
        acc[0][ct] = __builtin_amdgcn_mfma_f32_16x16x32_bf16(a[0][ks], b, acc[0][ct], 0, 0, 0);
        acc[1][ct] = __builtin_amdgcn_mfma_f32_16x16x32_bf16(a[1][ks], b, acc[1][ct], 0, 0, 0);
      }
    }
  }

#pragma unroll
  for (int t = 0; t < 2; ++t)
#pragma unroll
    for (int ct = 0; ct < 8; ++ct)
#pragma unroll
      for (int r = 0; r < 4; ++r) {
        int row = w * 32 + t * 16 + hi * 4 + r;
        int col = ct * 16 + lr;
        float v = fmaxf(acc[t][ct][r], 0.f);
        int byte = (row * 256 + col * 2) ^ ((row & 7) << 4);
        *(unsigned short*)&hsb[byte] = (unsigned short)bf16rne(v);
      }
  __syncthreads();

  bf16x8 a2[2][4];
#pragma unroll
  for (int t = 0; t < 2; ++t) {
    int row = w * 32 + t * 16 + lr;
    int xr = (row & 7) << 4;
#pragma unroll
    for (int ks = 0; ks < 4; ++ks)
      a2[t][ks] = *(const bf16x8*)&hsb[(row * 256 + ks * 64 + hi * 16) ^ xr];
  }

#pragma unroll
  for (int ct = 0; ct < 8; ++ct) {
    float bb = b2[ct * 16 + lr];
    acc[0][ct] = (f32x4){bb, bb, bb, bb};
    acc[1][ct] = acc[0][ct];
  }

  const char* wbase2 = (const char*)Wt2 + ((size_t)lr * 128 + hi * 8) * 2;
#pragma unroll
  for (int p = 0; p < 2; ++p) {
    const char* wp = wbase2 + p * 32768;
#pragma unroll
    for (int ct = 0; ct < 8; ++ct) {
#pragma unroll
      for (int ks = 0; ks < 4; ++ks) {
        bf16x8 b = *(const bf16x8*)(wp + ct * 4096 + ks * 64);
        acc[0][ct] = __builtin_amdgcn_mfma_f32_16x16x32_bf16(a2[0][ks], b, acc[0][ct], 0, 0, 0);
        acc[1][ct] = __builtin_amdgcn_mfma_f32_16x16x32_bf16(a2[1][ks], b, acc[1][ct], 0, 0, 0);
      }
    }
  }

#pragma unroll
  for (int t = 0; t < 2; ++t)
#pragma unroll
    for (int ct = 0; ct < 8; ++ct)
#pragma unroll
      for (int r = 0; r < 4; ++r) {
        int node = node0 + w * 32 + t * 16 + hi * 4 + r;
        if (node < n) {
          int col = ct * 16 + lr;
          float v = acc[t][ct][r];
          if (fout) fout[(size_t)node * DD + col] = v;
          if (hbout) hbout[(size_t)node * DD + col] = (unsigned short)bf16rne(v);
        }
      }
}

// ---------- classifier ----------
__global__ __launch_bounds__(256) void classifier_k(const float* __restrict__ h,
                                                    const float* __restrict__ Wc,
                                                    const float* __restrict__ bc,
                                                    float* __restrict__ out, int n) {
  __shared__ float wcs[DD * 16];
  for (int i = threadIdx.x; i < DD * 16; i += 256) wcs[i] = Wc[i];
  __syncthreads();
  int t = blockIdx.x * 256 + threadIdx.x;
  int node = t >> 4, c = t & 15;
  if (node >= n) return;
  float acc = bc[c];
  const float* hr = h + (size_t)node * DD;
#pragma unroll 8
  for (int k = 0; k < DD; ++k) acc += hr[k] * wcs[k * 16 + c];
  out[(size_t)node * 16 + c] = acc;
}

extern "C" void kernel_launch(void* const* d_in, const int* in_sizes, int n_in,
                              void* d_out, int out_size, void* d_ws, size_t ws_size,
                              hipStream_t stream) {
  const float* x = (const float*)d_in[0];
  const int* ei = (const int*)d_in[1];
  const float* W1 = (const float*)d_in[2];
  const float* b1 = (const float*)d_in[3];
  const float* W2 = (const float*)d_in[4];
  const float* b2 = (const float*)d_in[5];
  const float* Wc = (const float*)d_in[6];
  const float* bc = (const float*)d_in[7];

  const int N = in_sizes[0] / DD;
  const int E = in_sizes[1] / 2;
  const int* src = ei;
  const int* dst = ei + E;
  const int NB = (N + 127) >> 7;

  float* outp = (float*)d_out;
  float* h_final = outp;
  float* logits = outp + (size_t)N * DD;

  char* ws = (char*)d_ws;
  size_t off = 0;
  auto alloc = [&](size_t bytes) {
    char* p = ws + off;
    off = (off + bytes + 255) & ~(size_t)255;
    return p;
  };
  unsigned int* zb = (unsigned int*)alloc((size_t)N * 64 * 4);   // packed bf16 z
  unsigned int* hb = (unsigned int*)alloc((size_t)N * 64 * 4);   // packed bf16 h
  short* wt = (short*)alloc((size_t)3 * 2 * 2 * 16384 * 2);      // split transposed W
  int* bucketCount = (int*)alloc(NBMAX * 4);
  int* bucketOff = (int*)alloc((NBMAX + 1) * 4);
  int* gCursor = (int*)alloc(NBMAX * 4);
  int* rs = (int*)alloc((size_t)(N + 1) * 4);
  unsigned int* bucketed = (unsigned int*)alloc((size_t)E * 4);
  unsigned short* ssrc = (unsigned short*)alloc((size_t)E * 2);

  const int gEdge = (E + CHUNK - 1) / CHUNK;
  const int gGatherC = (N + 7) / 8;  // 8 nodes/block (2 per wave)
  const int gMlp = (N + 63) / 64;

  // CSR build
  hipMemsetAsync(bucketCount, 0, NBMAX * 4, stream);
  s1_hist<<<gEdge, 256, 0, stream>>>(dst, bucketCount, E);
  s2_scan<<<1, 256, 0, stream>>>(bucketCount, bucketOff, gCursor, rs, NB, N, E);
  s3_scatter<<<gEdge, 256, 0, stream>>>(src, dst, gCursor, bucketed, E, NB);
  s4_fill<<<NB, 256, 0, stream>>>(bucketed, bucketOff, rs, ssrc, N);

  // weight prep + x -> bf16
  prep_w<<<(3 * 2 * 16384 + 255) / 256, 256, 0, stream>>>(W1, W2, wt);
  conv_bf16<<<(N * 64 + 255) / 256, 256, 0, stream>>>(x, hb, N * 64);

  auto WT = [&](int layer, int mat) { return wt + ((size_t)(layer * 2 + mat)) * 2 * 16384; };

  // layer 0
  gather_chunk<<<gGatherC, 256, 0, stream>>>(hb, rs, ssrc, zb, N, 0);
  gather_chunk<<<gGatherC, 256, 0, stream>>>(hb, rs, ssrc, zb, N, 1);
  mlp_mfma<<<gMlp, 128, 0, stream>>>(zb, WT(0, 0), WT(0, 1), b1, b2,
                                     nullptr, (unsigned short*)hb, N);
  // layer 1
  gather_chunk<<<gGatherC, 256, 0, stream>>>(hb, rs, ssrc, zb, N, 0);
  gather_chunk<<<gGatherC, 256, 0, stream>>>(hb, rs, ssrc, zb, N, 1);
  mlp_mfma<<<gMlp, 128, 0, stream>>>(zb, WT(1, 0), WT(1, 1), b1 + DD, b2 + DD,
                                     nullptr, (unsigned short*)hb, N);
  // layer 2 -> f32 output
  gather_chunk<<<gGatherC, 256, 0, stream>>>(hb, rs, ssrc, zb, N, 0);
  gather_chunk<<<gGatherC, 256, 0, stream>>>(hb, rs, ssrc, zb, N, 1);
  mlp_mfma<<<gMlp, 128, 0, stream>>>(zb, WT(2, 0), WT(2, 1), b1 + 2 * DD, b2 + 2 * DD,
                                     h_final, nullptr, N);

  classifier_k<<<(N * 16 + 255) / 256, 256, 0, stream>>>(h_final, Wc, bc, logits, N);
}

// Round 5
// 325.888 us; speedup vs baseline: 1.2503x; 1.2503x over previous
//
#include <hip/hip_runtime.h>

#define DD 128
#define CHUNK 6144   // edges per block in S1/S3
#define NBMAX 512    // max buckets (N <= 65536)
#define SCAP 8192    // per-bucket LDS staging capacity

typedef __attribute__((ext_vector_type(8))) short bf16x8;
typedef __attribute__((ext_vector_type(4))) float f32x4;

// ---------- bf16 helpers ----------
__device__ __forceinline__ unsigned bf16rne(float f) {
  unsigned u = __float_as_uint(f);
  return (u + 0x7FFFu + ((u >> 16) & 1u)) >> 16;
}
__device__ __forceinline__ unsigned packbf(float lo, float hi) {
  return bf16rne(lo) | (bf16rne(hi) << 16);
}
__device__ __forceinline__ float bflo(unsigned v) { return __uint_as_float(v << 16); }
__device__ __forceinline__ float bfhi(unsigned v) { return __uint_as_float(v & 0xFFFF0000u); }

// ---------- inclusive block scan over LDS array (256 threads, nb <= 512) ----------
__device__ void block_scan_incl(int* cnt, int* inc, int nb, int tid) {
  for (int i = tid; i < nb; i += 256) inc[i] = cnt[i];
  __syncthreads();
  for (int d = 1; d < nb; d <<= 1) {
    int i0 = tid, i1 = tid + 256;
    int v0 = 0, v1 = 0;
    if (i0 < nb && i0 >= d) v0 = inc[i0 - d];
    if (i1 < nb && i1 >= d) v1 = inc[i1 - d];
    __syncthreads();
    if (i0 < nb) inc[i0] += v0;
    if (i1 < nb) inc[i1] += v1;
    __syncthreads();
  }
}

// ---------- S1: bucket histogram (bucket = dst >> 7) ----------
__global__ __launch_bounds__(256) void s1_hist(const int* __restrict__ dst,
                                               int* __restrict__ bucketCount, int e) {
  __shared__ int h[NBMAX];
  int tid = threadIdx.x;
  for (int i = tid; i < NBMAX; i += 256) h[i] = 0;
  __syncthreads();
  int i0 = blockIdx.x * CHUNK;
  int i1 = min(i0 + CHUNK, e);
  for (int i = i0 + tid; i < i1; i += 256) atomicAdd(&h[dst[i] >> 7], 1);
  __syncthreads();
  for (int i = tid; i < NBMAX; i += 256)
    if (h[i]) atomicAdd(&bucketCount[i], h[i]);
}

// ---------- S2: scan bucket counts ----------
__global__ __launch_bounds__(256) void s2_scan(const int* __restrict__ bucketCount,
                                               int* __restrict__ bucketOff,
                                               int* __restrict__ gCursor,
                                               int* __restrict__ rs, int nb, int n, int e) {
  __shared__ int cnt[NBMAX], inc[NBMAX];
  int tid = threadIdx.x;
  for (int i = tid; i < nb; i += 256) cnt[i] = bucketCount[i];
  __syncthreads();
  block_scan_incl(cnt, inc, nb, tid);
  for (int i = tid; i < nb; i += 256) {
    int off = inc[i] - cnt[i];
    bucketOff[i] = off;
    gCursor[i] = off;
  }
  if (tid == 0) { bucketOff[nb] = e; rs[n] = e; }
}

// ---------- S3: block-local grouping + coalesced bucket scatter ----------
__global__ __launch_bounds__(256) void s3_scatter(const int* __restrict__ src,
                                                  const int* __restrict__ dst,
                                                  int* __restrict__ gCursor,
                                                  unsigned int* __restrict__ bucketed,
                                                  int e, int nb) {
  __shared__ int cnt[NBMAX], inc[NBMAX], base[NBMAX], cur[NBMAX];
  __shared__ unsigned int pairs[CHUNK];
  int tid = threadIdx.x;
  for (int i = tid; i < nb; i += 256) cnt[i] = 0;
  __syncthreads();
  int i0 = blockIdx.x * CHUNK;
  int i1 = min(i0 + CHUNK, e);
  for (int i = i0 + tid; i < i1; i += 256) atomicAdd(&cnt[dst[i] >> 7], 1);
  __syncthreads();
  block_scan_incl(cnt, inc, nb, tid);
  for (int b = tid; b < nb; b += 256) {
    int c = cnt[b];
    base[b] = c ? atomicAdd(&gCursor[b], c) : 0;
    cur[b] = inc[b] - c;
  }
  __syncthreads();
  for (int i = i0 + tid; i < i1; i += 256) {
    int d = dst[i];
    int p = atomicAdd(&cur[d >> 7], 1);
    pairs[p] = (unsigned)d | ((unsigned)src[i] << 16);
  }
  __syncthreads();
  int m = i1 - i0;
  for (int i = tid; i < m; i += 256) {
    unsigned w = pairs[i];
    int b = (int)(w & 0xFFFFu) >> 7;
    bucketed[base[b] + (i - (inc[b] - cnt[b]))] = w;
  }
}

// ---------- S4: per-bucket node-level fill; emits rs[] and u16 ssrc ----------
__global__ __launch_bounds__(256) void s4_fill(const unsigned int* __restrict__ bucketed,
                                               const int* __restrict__ bucketOff,
                                               int* __restrict__ rs,
                                               unsigned short* __restrict__ ssrc, int n) {
  __shared__ int cnt[128], inc[128], cur[128];
  __shared__ unsigned short outb[SCAP];
  int b = blockIdx.x;
  int bo = bucketOff[b], b1 = bucketOff[b + 1];
  int len = b1 - bo;
  int tid = threadIdx.x;
  int n0 = b << 7;
  if (tid < 128) cnt[tid] = 0;
  __syncthreads();
  for (int i = tid; i < len; i += 256) atomicAdd(&cnt[bucketed[bo + i] & 127], 1);
  __syncthreads();
  if (tid < 128) inc[tid] = cnt[tid];
  __syncthreads();
  for (int d = 1; d < 128; d <<= 1) {
    int v = 0;
    if (tid < 128 && tid >= d) v = inc[tid - d];
    __syncthreads();
    if (tid < 128) inc[tid] += v;
    __syncthreads();
  }
  if (tid < 128) {
    int off = inc[tid] - cnt[tid];
    cur[tid] = off;
    int node = n0 + tid;
    if (node < n) rs[node] = bo + off;
  }
  __syncthreads();
  if (len <= SCAP) {
    for (int i = tid; i < len; i += 256) {
      unsigned w = bucketed[bo + i];
      int p = atomicAdd(&cur[w & 127], 1);
      outb[p] = (unsigned short)(w >> 16);
    }
    __syncthreads();
    for (int i = tid; i < len; i += 256) ssrc[bo + i] = outb[i];
  } else {
    for (int i = tid; i < len; i += 256) {
      unsigned w = bucketed[bo + i];
      int p = atomicAdd(&cur[w & 127], 1);
      ssrc[bo + p] = (unsigned short)(w >> 16);
    }
  }
}

// ---------- conv: f32 -> packed bf16x2 ----------
__global__ __launch_bounds__(256) void conv_bf16(const float* __restrict__ x,
                                                 unsigned int* __restrict__ hb, int n64) {
  int i = blockIdx.x * 256 + threadIdx.x;
  if (i < n64) {
    float2 v = ((const float2*)x)[i];
    hb[i] = packbf(v.x, v.y);
  }
}

// ---------- W prep: split W into (hi, lo) bf16, PRE-SWIZZLED [col][k] image ----------
// Linear image byte offset for (col,k): col*256 + k*2; stored at lin ^ ((col&7)<<4),
// i.e. short index col*128 + (k ^ ((col&7)<<3)). LDS staging is then a linear copy
// and ds_reads apply the same XOR.
__global__ __launch_bounds__(256) void prep_w(const float* __restrict__ W1,
                                              const float* __restrict__ W2,
                                              short* __restrict__ wt) {
  int idx = blockIdx.x * 256 + threadIdx.x;  // 3*2*16384
  if (idx >= 3 * 2 * 16384) return;
  int lm = idx >> 14;      // layer*2 + mat
  int e = idx & 16383;
  int k = e >> 7;
  int col = e & 127;
  int layer = lm >> 1, mat = lm & 1;
  const float* W = mat ? W2 : W1;
  float w = W[layer * 16384 + k * 128 + col];
  unsigned short h = (unsigned short)bf16rne(w);
  float hv = __uint_as_float((unsigned)h << 16);
  unsigned short lo = (unsigned short)bf16rne(w - hv);
  size_t base = (size_t)lm * 2 * 16384;
  int ksw = k ^ ((col & 7) << 3);  // swizzled k position
  wt[base + col * 128 + ksw] = (short)h;
  wt[base + 16384 + col * 128 + ksw] = (short)lo;
}

// ---------- aggregation: zb = hb_i + sum_{j->i} hb_j (f32 accum, bf16 out) ----------
__global__ __launch_bounds__(256) void gather_zb(const unsigned int* __restrict__ hb,
                                                 const int* __restrict__ rs,
                                                 const unsigned short* __restrict__ ssrc,
                                                 unsigned int* __restrict__ zb, int n) {
  int node = blockIdx.x * 4 + (threadIdx.x >> 6);
  if (node >= n) return;
  int lane = threadIdx.x & 63;
  int s0 = rs[node], s1 = rs[node + 1];
  unsigned v = hb[(size_t)node * 64 + lane];
  float ax = bflo(v), ay = bfhi(v);
  int t = s0;
  for (; t + 3 < s1; t += 4) {
    int sa = ssrc[t], sb = ssrc[t + 1], sc = ssrc[t + 2], sd = ssrc[t + 3];
    unsigned va = hb[(size_t)sa * 64 + lane];
    unsigned vb = hb[(size_t)sb * 64 + lane];
    unsigned vc = hb[(size_t)sc * 64 + lane];
    unsigned vd = hb[(size_t)sd * 64 + lane];
    ax += bflo(va) + bflo(vb) + bflo(vc) + bflo(vd);
    ay += bfhi(va) + bfhi(vb) + bfhi(vc) + bfhi(vd);
  }
  for (; t < s1; ++t) {
    unsigned vv = hb[(size_t)ssrc[t] * 64 + lane];
    ax += bflo(vv);
    ay += bfhi(vv);
  }
  zb[(size_t)node * 64 + lane] = packbf(ax, ay);
}

// ---------- MFMA MLP: hout = relu(z@W1+b1)@W2+b2 ----------
// 256 threads = 4 waves in 2x2: wave w -> rows (w&1)*64..+64, cols (w>>1)*64..+64.
// Each B-fragment ds_read feeds 4 MFMAs. Weights staged to LDS in 4x 32KB phases.
__global__ __launch_bounds__(256, 2) void mlp_mfma(
    const unsigned int* __restrict__ zb,
    const short* __restrict__ Wt1, const short* __restrict__ Wt2,
    const float* __restrict__ b1, const float* __restrict__ b2,
    float* __restrict__ fout, unsigned short* __restrict__ hbout, int n) {
  __shared__ char wbuf[32768];      // one weight part (swizzled image)
  __shared__ char hsb[128 * 256];   // 32KB swizzled bf16 h-tile
  int tid = threadIdx.x;
  int w = tid >> 6, lane = tid & 63;
  int lr = lane & 15, hi = lane >> 4;
  int wr = (w & 1) * 64;   // wave row offset in block
  int wc = (w >> 1) * 64;  // wave col offset
  int node0 = blockIdx.x * 128;

  // A1 frags from global zb (bf16 rows); waves with same wr duplicate (L1-hit)
  bf16x8 a[4][4];
#pragma unroll
  for (int t = 0; t < 4; ++t) {
    int row = node0 + wr + t * 16 + lr;
    row = min(row, n - 1);
    const char* rp = (const char*)(zb + (size_t)row * 64);
#pragma unroll
    for (int ks = 0; ks < 4; ++ks)
      a[t][ks] = *(const bf16x8*)(rp + ks * 64 + hi * 16);
  }

  f32x4 acc[4][4];
#pragma unroll
  for (int ct = 0; ct < 4; ++ct) {
    float bb = b1[wc + ct * 16 + lr];
#pragma unroll
    for (int t = 0; t < 4; ++t) acc[t][ct] = (f32x4){bb, bb, bb, bb};
  }

  // matmul1: z @ W1, parts hi(p=0), lo(p=1) both accumulate
#pragma unroll
  for (int p = 0; p < 2; ++p) {
    __syncthreads();  // prior wbuf reads done
    {
      const char* gs = (const char*)(Wt1 + p * 16384);
      for (int i = tid * 16; i < 32768; i += 256 * 16)
        *(float4*)&wbuf[i] = *(const float4*)(gs + i);
    }
    __syncthreads();
#pragma unroll
    for (int ct = 0; ct < 4; ++ct) {
      int col = wc + ct * 16 + lr;
      int cx = (col & 7) << 4;
#pragma unroll
      for (int ks = 0; ks < 4; ++ks) {
        bf16x8 b = *(const bf16x8*)&wbuf[(col * 256 + ks * 64 + hi * 16) ^ cx];
#pragma unroll
        for (int t = 0; t < 4; ++t)
          acc[t][ct] = __builtin_amdgcn_mfma_f32_16x16x32_bf16(a[t][ks], b, acc[t][ct], 0, 0, 0);
      }
    }
  }

  // relu -> swizzled LDS bf16 (C layout: row=(lane>>4)*4+r, col=lane&15)
#pragma unroll
  for (int t = 0; t < 4; ++t)
#pragma unroll
    for (int ct = 0; ct < 4; ++ct)
#pragma unroll
      for (int r = 0; r < 4; ++r) {
        int row = wr + t * 16 + hi * 4 + r;
        int col = wc + ct * 16 + lr;
        float v = fmaxf(acc[t][ct][r], 0.f);
        int byte = (row * 256 + col * 2) ^ ((row & 7) << 4);
        *(unsigned short*)&hsb[byte] = (unsigned short)bf16rne(v);
      }
  __syncthreads();

  // A2 frags from LDS (full K rows of this wave's 64 rows)
  bf16x8 a2[4][4];
#pragma unroll
  for (int t = 0; t < 4; ++t) {
    int row = wr + t * 16 + lr;
    int xr = (row & 7) << 4;
#pragma unroll
    for (int ks = 0; ks < 4; ++ks)
      a2[t][ks] = *(const bf16x8*)&hsb[(row * 256 + ks * 64 + hi * 16) ^ xr];
  }

#pragma unroll
  for (int ct = 0; ct < 4; ++ct) {
    float bb = b2[wc + ct * 16 + lr];
#pragma unroll
    for (int t = 0; t < 4; ++t) acc[t][ct] = (f32x4){bb, bb, bb, bb};
  }

  // matmul2: h @ W2
#pragma unroll
  for (int p = 0; p < 2; ++p) {
    __syncthreads();
    {
      const char* gs = (const char*)(Wt2 + p * 16384);
      for (int i = tid * 16; i < 32768; i += 256 * 16)
        *(float4*)&wbuf[i] = *(const float4*)(gs + i);
    }
    __syncthreads();
#pragma unroll
    for (int ct = 0; ct < 4; ++ct) {
      int col = wc + ct * 16 + lr;
      int cx = (col & 7) << 4;
#pragma unroll
      for (int ks = 0; ks < 4; ++ks) {
        bf16x8 b = *(const bf16x8*)&wbuf[(col * 256 + ks * 64 + hi * 16) ^ cx];
#pragma unroll
        for (int t = 0; t < 4; ++t)
          acc[t][ct] = __builtin_amdgcn_mfma_f32_16x16x32_bf16(a2[t][ks], b, acc[t][ct], 0, 0, 0);
      }
    }
  }

  // store
#pragma unroll
  for (int t = 0; t < 4; ++t)
#pragma unroll
    for (int ct = 0; ct < 4; ++ct)
#pragma unroll
      for (int r = 0; r < 4; ++r) {
        int node = node0 + wr + t * 16 + hi * 4 + r;
        if (node < n) {
          int col = wc + ct * 16 + lr;
          float v = acc[t][ct][r];
          if (fout) fout[(size_t)node * DD + col] = v;
          if (hbout) hbout[(size_t)node * DD + col] = (unsigned short)bf16rne(v);
        }
      }
}

// ---------- classifier ----------
__global__ __launch_bounds__(256) void classifier_k(const float* __restrict__ h,
                                                    const float* __restrict__ Wc,
                                                    const float* __restrict__ bc,
                                                    float* __restrict__ out, int n) {
  __shared__ float wcs[DD * 16];
  for (int i = threadIdx.x; i < DD * 16; i += 256) wcs[i] = Wc[i];
  __syncthreads();
  int t = blockIdx.x * 256 + threadIdx.x;
  int node = t >> 4, c = t & 15;
  if (node >= n) return;
  float acc = bc[c];
  const float* hr = h + (size_t)node * DD;
#pragma unroll 8
  for (int k = 0; k < DD; ++k) acc += hr[k] * wcs[k * 16 + c];
  out[(size_t)node * 16 + c] = acc;
}

extern "C" void kernel_launch(void* const* d_in, const int* in_sizes, int n_in,
                              void* d_out, int out_size, void* d_ws, size_t ws_size,
                              hipStream_t stream) {
  const float* x = (const float*)d_in[0];
  const int* ei = (const int*)d_in[1];
  const float* W1 = (const float*)d_in[2];
  const float* b1 = (const float*)d_in[3];
  const float* W2 = (const float*)d_in[4];
  const float* b2 = (const float*)d_in[5];
  const float* Wc = (const float*)d_in[6];
  const float* bc = (const float*)d_in[7];

  const int N = in_sizes[0] / DD;
  const int E = in_sizes[1] / 2;
  const int* src = ei;
  const int* dst = ei + E;
  const int NB = (N + 127) >> 7;

  float* outp = (float*)d_out;
  float* h_final = outp;
  float* logits = outp + (size_t)N * DD;

  char* ws = (char*)d_ws;
  size_t off = 0;
  auto alloc = [&](size_t bytes) {
    char* p = ws + off;
    off = (off + bytes + 255) & ~(size_t)255;
    return p;
  };
  unsigned int* zb = (unsigned int*)alloc((size_t)N * 64 * 4);   // packed bf16 z
  unsigned int* hb = (unsigned int*)alloc((size_t)N * 64 * 4);   // packed bf16 h
  short* wt = (short*)alloc((size_t)3 * 2 * 2 * 16384 * 2);      // split swizzled W
  int* bucketCount = (int*)alloc(NBMAX * 4);
  int* bucketOff = (int*)alloc((NBMAX + 1) * 4);
  int* gCursor = (int*)alloc(NBMAX * 4);
  int* rs = (int*)alloc((size_t)(N + 1) * 4);
  unsigned int* bucketed = (unsigned int*)alloc((size_t)E * 4);
  unsigned short* ssrc = (unsigned short*)alloc((size_t)E * 2);

  const int gEdge = (E + CHUNK - 1) / CHUNK;
  const int gGather = (N + 3) / 4;
  const int gMlp = (N + 127) / 128;

  // CSR build
  hipMemsetAsync(bucketCount, 0, NBMAX * 4, stream);
  s1_hist<<<gEdge, 256, 0, stream>>>(dst, bucketCount, E);
  s2_scan<<<1, 256, 0, stream>>>(bucketCount, bucketOff, gCursor, rs, NB, N, E);
  s3_scatter<<<gEdge, 256, 0, stream>>>(src, dst, gCursor, bucketed, E, NB);
  s4_fill<<<NB, 256, 0, stream>>>(bucketed, bucketOff, rs, ssrc, N);

  // weight prep + x -> bf16
  prep_w<<<(3 * 2 * 16384 + 255) / 256, 256, 0, stream>>>(W1, W2, wt);
  conv_bf16<<<(N * 64 + 255) / 256, 256, 0, stream>>>(x, hb, N * 64);

  auto WT = [&](int layer, int mat) { return wt + ((size_t)(layer * 2 + mat)) * 2 * 16384; };

  // layer 0
  gather_zb<<<gGather, 256, 0, stream>>>(hb, rs, ssrc, zb, N);
  mlp_mfma<<<gMlp, 256, 0, stream>>>(zb, WT(0, 0), WT(0, 1), b1, b2,
                                     nullptr, (unsigned short*)hb, N);
  // layer 1
  gather_zb<<<gGather, 256, 0, stream>>>(hb, rs, ssrc, zb, N);
  mlp_mfma<<<gMlp, 256, 0, stream>>>(zb, WT(1, 0), WT(1, 1), b1 + DD, b2 + DD,
                                     nullptr, (unsigned short*)hb, N);
  // layer 2 -> f32 output
  gather_zb<<<gGather, 256, 0, stream>>>(hb, rs, ssrc, zb, N);
  mlp_mfma<<<gMlp, 256, 0, stream>>>(zb, WT(2, 0), WT(2, 1), b1 + 2 * DD, b2 + 2 * DD,
                                     h_final, nullptr, N);

  classifier_k<<<(N * 16 + 255) / 256, 256, 0, stream>>>(h_final, Wc, bc, logits, N);
}

// Round 6
// 294.363 us; speedup vs baseline: 1.3842x; 1.1071x over previous
//
#include <hip/hip_runtime.h>

#define DD 128
#define CHUNK 6144   // edges per block in S1/S3
#define NBMAX 512    // max buckets (N <= 65536)
#define SCAP 8192    // per-bucket LDS staging capacity

typedef __attribute__((ext_vector_type(8))) short bf16x8;
typedef __attribute__((ext_vector_type(4))) float f32x4;

// ---------- bf16 helpers ----------
__device__ __forceinline__ unsigned bf16rne(float f) {
  unsigned u = __float_as_uint(f);
  return (u + 0x7FFFu + ((u >> 16) & 1u)) >> 16;
}
__device__ __forceinline__ unsigned packbf(float lo, float hi) {
  return bf16rne(lo) | (bf16rne(hi) << 16);
}
__device__ __forceinline__ float bflo(unsigned v) { return __uint_as_float(v << 16); }
__device__ __forceinline__ float bfhi(unsigned v) { return __uint_as_float(v & 0xFFFF0000u); }

// ---------- inclusive block scan over LDS array (256 threads, nb <= 512) ----------
__device__ void block_scan_incl(int* cnt, int* inc, int nb, int tid) {
  for (int i = tid; i < nb; i += 256) inc[i] = cnt[i];
  __syncthreads();
  for (int d = 1; d < nb; d <<= 1) {
    int i0 = tid, i1 = tid + 256;
    int v0 = 0, v1 = 0;
    if (i0 < nb && i0 >= d) v0 = inc[i0 - d];
    if (i1 < nb && i1 >= d) v1 = inc[i1 - d];
    __syncthreads();
    if (i0 < nb) inc[i0] += v0;
    if (i1 < nb) inc[i1] += v1;
    __syncthreads();
  }
}

// ---------- S1: bucket histogram (bucket = dst >> 7) ----------
__global__ __launch_bounds__(256) void s1_hist(const int* __restrict__ dst,
                                               int* __restrict__ bucketCount, int e) {
  __shared__ int h[NBMAX];
  int tid = threadIdx.x;
  for (int i = tid; i < NBMAX; i += 256) h[i] = 0;
  __syncthreads();
  int i0 = blockIdx.x * CHUNK;
  int i1 = min(i0 + CHUNK, e);
  for (int i = i0 + tid; i < i1; i += 256) atomicAdd(&h[dst[i] >> 7], 1);
  __syncthreads();
  for (int i = tid; i < NBMAX; i += 256)
    if (h[i]) atomicAdd(&bucketCount[i], h[i]);
}

// ---------- S2: scan bucket counts ----------
__global__ __launch_bounds__(256) void s2_scan(const int* __restrict__ bucketCount,
                                               int* __restrict__ bucketOff,
                                               int* __restrict__ gCursor,
                                               int* __restrict__ rs, int nb, int n, int e) {
  __shared__ int cnt[NBMAX], inc[NBMAX];
  int tid = threadIdx.x;
  for (int i = tid; i < nb; i += 256) cnt[i] = bucketCount[i];
  __syncthreads();
  block_scan_incl(cnt, inc, nb, tid);
  for (int i = tid; i < nb; i += 256) {
    int off = inc[i] - cnt[i];
    bucketOff[i] = off;
    gCursor[i] = off;
  }
  if (tid == 0) { bucketOff[nb] = e; rs[n] = e; }
}

// ---------- S3: block-local grouping + coalesced bucket scatter ----------
__global__ __launch_bounds__(256) void s3_scatter(const int* __restrict__ src,
                                                  const int* __restrict__ dst,
                                                  int* __restrict__ gCursor,
                                                  unsigned int* __restrict__ bucketed,
                                                  int e, int nb) {
  __shared__ int cnt[NBMAX], inc[NBMAX], base[NBMAX], cur[NBMAX];
  __shared__ unsigned int pairs[CHUNK];
  int tid = threadIdx.x;
  for (int i = tid; i < nb; i += 256) cnt[i] = 0;
  __syncthreads();
  int i0 = blockIdx.x * CHUNK;
  int i1 = min(i0 + CHUNK, e);
  for (int i = i0 + tid; i < i1; i += 256) atomicAdd(&cnt[dst[i] >> 7], 1);
  __syncthreads();
  block_scan_incl(cnt, inc, nb, tid);
  for (int b = tid; b < nb; b += 256) {
    int c = cnt[b];
    base[b] = c ? atomicAdd(&gCursor[b], c) : 0;
    cur[b] = inc[b] - c;
  }
  __syncthreads();
  for (int i = i0 + tid; i < i1; i += 256) {
    int d = dst[i];
    int p = atomicAdd(&cur[d >> 7], 1);
    pairs[p] = (unsigned)d | ((unsigned)src[i] << 16);
  }
  __syncthreads();
  int m = i1 - i0;
  for (int i = tid; i < m; i += 256) {
    unsigned w = pairs[i];
    int b = (int)(w & 0xFFFFu) >> 7;
    bucketed[base[b] + (i - (inc[b] - cnt[b]))] = w;
  }
}

// ---------- S4: per-bucket node-level fill; emits rs[] and u16 ssrc ----------
__global__ __launch_bounds__(256) void s4_fill(const unsigned int* __restrict__ bucketed,
                                               const int* __restrict__ bucketOff,
                                               int* __restrict__ rs,
                                               unsigned short* __restrict__ ssrc, int n) {
  __shared__ int cnt[128], inc[128], cur[128];
  __shared__ unsigned short outb[SCAP];
  int b = blockIdx.x;
  int bo = bucketOff[b], b1 = bucketOff[b + 1];
  int len = b1 - bo;
  int tid = threadIdx.x;
  int n0 = b << 7;
  if (tid < 128) cnt[tid] = 0;
  __syncthreads();
  for (int i = tid; i < len; i += 256) atomicAdd(&cnt[bucketed[bo + i] & 127], 1);
  __syncthreads();
  if (tid < 128) inc[tid] = cnt[tid];
  __syncthreads();
  for (int d = 1; d < 128; d <<= 1) {
    int v = 0;
    if (tid < 128 && tid >= d) v = inc[tid - d];
    __syncthreads();
    if (tid < 128) inc[tid] += v;
    __syncthreads();
  }
  if (tid < 128) {
    int off = inc[tid] - cnt[tid];
    cur[tid] = off;
    int node = n0 + tid;
    if (node < n) rs[node] = bo + off;
  }
  __syncthreads();
  if (len <= SCAP) {
    for (int i = tid; i < len; i += 256) {
      unsigned w = bucketed[bo + i];
      int p = atomicAdd(&cur[w & 127], 1);
      outb[p] = (unsigned short)(w >> 16);
    }
    __syncthreads();
    for (int i = tid; i < len; i += 256) ssrc[bo + i] = outb[i];
  } else {
    for (int i = tid; i < len; i += 256) {
      unsigned w = bucketed[bo + i];
      int p = atomicAdd(&cur[w & 127], 1);
      ssrc[bo + p] = (unsigned short)(w >> 16);
    }
  }
}

// ---------- conv: f32 -> packed bf16x2 ----------
__global__ __launch_bounds__(256) void conv_bf16(const float* __restrict__ x,
                                                 unsigned int* __restrict__ hb, int n64) {
  int i = blockIdx.x * 256 + threadIdx.x;
  if (i < n64) {
    float2 v = ((const float2*)x)[i];
    hb[i] = packbf(v.x, v.y);
  }
}

// ---------- W prep: split W into (hi, lo) bf16, PRE-SWIZZLED [col][k] image ----------
__global__ __launch_bounds__(256) void prep_w(const float* __restrict__ W1,
                                              const float* __restrict__ W2,
                                              short* __restrict__ wt) {
  int idx = blockIdx.x * 256 + threadIdx.x;  // 3*2*16384
  if (idx >= 3 * 2 * 16384) return;
  int lm = idx >> 14;      // layer*2 + mat
  int e = idx & 16383;
  int k = e >> 7;
  int col = e & 127;
  int layer = lm >> 1, mat = lm & 1;
  const float* W = mat ? W2 : W1;
  float w = W[layer * 16384 + k * 128 + col];
  unsigned short h = (unsigned short)bf16rne(w);
  float hv = __uint_as_float((unsigned)h << 16);
  unsigned short lo = (unsigned short)bf16rne(w - hv);
  size_t base = (size_t)lm * 2 * 16384;
  int ksw = k ^ ((col & 7) << 3);  // swizzled k position
  wt[base + col * 128 + ksw] = (short)h;
  wt[base + 16384 + col * 128 + ksw] = (short)lo;
}

// ---------- aggregation: software-pipelined depth-8 gather ----------
// Issue batch i+1's 8 row-loads BEFORE accumulating batch i -> ~8 wave-loads
// in flight per wave (was ~2-4), shifting from latency-bound to BW-bound.
__global__ __launch_bounds__(256) void gather_zb(const unsigned int* __restrict__ hb,
                                                 const int* __restrict__ rs,
                                                 const unsigned short* __restrict__ ssrc,
                                                 unsigned int* __restrict__ zb, int n) {
  int node = blockIdx.x * 4 + (threadIdx.x >> 6);
  if (node >= n) return;
  int lane = threadIdx.x & 63;
  int s0 = rs[node], s1 = rs[node + 1];
  unsigned v = hb[(size_t)node * 64 + lane];
  float ax = bflo(v), ay = bfhi(v);
  int last = s1 - 1;
  unsigned A[8], B[8];
  // prologue: batch 0 (clamped addr, value-masked)
#pragma unroll
  for (int i = 0; i < 8; ++i) {
    int t = s0 + i;
    unsigned val = hb[(size_t)ssrc[min(t, last)] * 64 + lane];
    A[i] = (t <= last) ? val : 0u;
  }
  for (int t = s0 + 8; t < s1; t += 8) {
    // issue next batch
#pragma unroll
    for (int i = 0; i < 8; ++i) {
      int u = t + i;
      unsigned val = hb[(size_t)ssrc[min(u, last)] * 64 + lane];
      B[i] = (u <= last) ? val : 0u;
    }
    // accumulate current batch
#pragma unroll
    for (int i = 0; i < 8; ++i) {
      ax += bflo(A[i]);
      ay += bfhi(A[i]);
    }
#pragma unroll
    for (int i = 0; i < 8; ++i) A[i] = B[i];
  }
#pragma unroll
  for (int i = 0; i < 8; ++i) {
    ax += bflo(A[i]);
    ay += bfhi(A[i]);
  }
  zb[(size_t)node * 64 + lane] = packbf(ax, ay);
}

// ---------- MFMA MLP: hout = relu(z@W1+b1)@W2+b2 ----------
// 256 threads = 4 waves in 2x2: wave w -> rows (w&1)*64..+64, cols (w>>1)*64..+64.
__global__ __launch_bounds__(256, 2) void mlp_mfma(
    const unsigned int* __restrict__ zb,
    const short* __restrict__ Wt1, const short* __restrict__ Wt2,
    const float* __restrict__ b1, const float* __restrict__ b2,
    float* __restrict__ fout, unsigned short* __restrict__ hbout, int n) {
  __shared__ char wbuf[32768];      // one weight part (swizzled image)
  __shared__ char hsb[128 * 256];   // 32KB swizzled bf16 h-tile
  int tid = threadIdx.x;
  int w = tid >> 6, lane = tid & 63;
  int lr = lane & 15, hi = lane >> 4;
  int wr = (w & 1) * 64;
  int wc = (w >> 1) * 64;
  int node0 = blockIdx.x * 128;

  bf16x8 a[4][4];
#pragma unroll
  for (int t = 0; t < 4; ++t) {
    int row = node0 + wr + t * 16 + lr;
    row = min(row, n - 1);
    const char* rp = (const char*)(zb + (size_t)row * 64);
#pragma unroll
    for (int ks = 0; ks < 4; ++ks)
      a[t][ks] = *(const bf16x8*)(rp + ks * 64 + hi * 16);
  }

  f32x4 acc[4][4];
#pragma unroll
  for (int ct = 0; ct < 4; ++ct) {
    float bb = b1[wc + ct * 16 + lr];
#pragma unroll
    for (int t = 0; t < 4; ++t) acc[t][ct] = (f32x4){bb, bb, bb, bb};
  }

#pragma unroll
  for (int p = 0; p < 2; ++p) {
    __syncthreads();
    {
      const char* gs = (const char*)(Wt1 + p * 16384);
      for (int i = tid * 16; i < 32768; i += 256 * 16)
        *(float4*)&wbuf[i] = *(const float4*)(gs + i);
    }
    __syncthreads();
#pragma unroll
    for (int ct = 0; ct < 4; ++ct) {
      int col = wc + ct * 16 + lr;
      int cx = (col & 7) << 4;
#pragma unroll
      for (int ks = 0; ks < 4; ++ks) {
        bf16x8 b = *(const bf16x8*)&wbuf[(col * 256 + ks * 64 + hi * 16) ^ cx];
#pragma unroll
        for (int t = 0; t < 4; ++t)
          acc[t][ct] = __builtin_amdgcn_mfma_f32_16x16x32_bf16(a[t][ks], b, acc[t][ct], 0, 0, 0);
      }
    }
  }

#pragma unroll
  for (int t = 0; t < 4; ++t)
#pragma unroll
    for (int ct = 0; ct < 4; ++ct)
#pragma unroll
      for (int r = 0; r < 4; ++r) {
        int row = wr + t * 16 + hi * 4 + r;
        int col = wc + ct * 16 + lr;
        float v = fmaxf(acc[t][ct][r], 0.f);
        int byte = (row * 256 + col * 2) ^ ((row & 7) << 4);
        *(unsigned short*)&hsb[byte] = (unsigned short)bf16rne(v);
      }
  __syncthreads();

  bf16x8 a2[4][4];
#pragma unroll
  for (int t = 0; t < 4; ++t) {
    int row = wr + t * 16 + lr;
    int xr = (row & 7) << 4;
#pragma unroll
    for (int ks = 0; ks < 4; ++ks)
      a2[t][ks] = *(const bf16x8*)&hsb[(row * 256 + ks * 64 + hi * 16) ^ xr];
  }

#pragma unroll
  for (int ct = 0; ct < 4; ++ct) {
    float bb = b2[wc + ct * 16 + lr];
#pragma unroll
    for (int t = 0; t < 4; ++t) acc[t][ct] = (f32x4){bb, bb, bb, bb};
  }

#pragma unroll
  for (int p = 0; p < 2; ++p) {
    __syncthreads();
    {
      const char* gs = (const char*)(Wt2 + p * 16384);
      for (int i = tid * 16; i < 32768; i += 256 * 16)
        *(float4*)&wbuf[i] = *(const float4*)(gs + i);
    }
    __syncthreads();
#pragma unroll
    for (int ct = 0; ct < 4; ++ct) {
      int col = wc + ct * 16 + lr;
      int cx = (col & 7) << 4;
#pragma unroll
      for (int ks = 0; ks < 4; ++ks) {
        bf16x8 b = *(const bf16x8*)&wbuf[(col * 256 + ks * 64 + hi * 16) ^ cx];
#pragma unroll
        for (int t = 0; t < 4; ++t)
          acc[t][ct] = __builtin_amdgcn_mfma_f32_16x16x32_bf16(a2[t][ks], b, acc[t][ct], 0, 0, 0);
      }
    }
  }

#pragma unroll
  for (int t = 0; t < 4; ++t)
#pragma unroll
    for (int ct = 0; ct < 4; ++ct)
#pragma unroll
      for (int r = 0; r < 4; ++r) {
        int node = node0 + wr + t * 16 + hi * 4 + r;
        if (node < n) {
          int col = wc + ct * 16 + lr;
          float v = acc[t][ct][r];
          if (fout) fout[(size_t)node * DD + col] = v;
          if (hbout) hbout[(size_t)node * DD + col] = (unsigned short)bf16rne(v);
        }
      }
}

// ---------- classifier ----------
__global__ __launch_bounds__(256) void classifier_k(const float* __restrict__ h,
                                                    const float* __restrict__ Wc,
                                                    const float* __restrict__ bc,
                                                    float* __restrict__ out, int n) {
  __shared__ float wcs[DD * 16];
  for (int i = threadIdx.x; i < DD * 16; i += 256) wcs[i] = Wc[i];
  __syncthreads();
  int t = blockIdx.x * 256 + threadIdx.x;
  int node = t >> 4, c = t & 15;
  if (node >= n) return;
  float acc = bc[c];
  const float* hr = h + (size_t)node * DD;
#pragma unroll 8
  for (int k = 0; k < DD; ++k) acc += hr[k] * wcs[k * 16 + c];
  out[(size_t)node * 16 + c] = acc;
}

extern "C" void kernel_launch(void* const* d_in, const int* in_sizes, int n_in,
                              void* d_out, int out_size, void* d_ws, size_t ws_size,
                              hipStream_t stream) {
  const float* x = (const float*)d_in[0];
  const int* ei = (const int*)d_in[1];
  const float* W1 = (const float*)d_in[2];
  const float* b1 = (const float*)d_in[3];
  const float* W2 = (const float*)d_in[4];
  const float* b2 = (const float*)d_in[5];
  const float* Wc = (const float*)d_in[6];
  const float* bc = (const float*)d_in[7];

  const int N = in_sizes[0] / DD;
  const int E = in_sizes[1] / 2;
  const int* src = ei;
  const int* dst = ei + E;
  const int NB = (N + 127) >> 7;

  float* outp = (float*)d_out;
  float* h_final = outp;
  float* logits = outp + (size_t)N * DD;

  char* ws = (char*)d_ws;
  size_t off = 0;
  auto alloc = [&](size_t bytes) {
    char* p = ws + off;
    off = (off + bytes + 255) & ~(size_t)255;
    return p;
  };
  unsigned int* zb = (unsigned int*)alloc((size_t)N * 64 * 4);   // packed bf16 z
  unsigned int* hb = (unsigned int*)alloc((size_t)N * 64 * 4);   // packed bf16 h
  short* wt = (short*)alloc((size_t)3 * 2 * 2 * 16384 * 2);      // split swizzled W
  int* bucketCount = (int*)alloc(NBMAX * 4);
  int* bucketOff = (int*)alloc((NBMAX + 1) * 4);
  int* gCursor = (int*)alloc(NBMAX * 4);
  int* rs = (int*)alloc((size_t)(N + 1) * 4);
  unsigned int* bucketed = (unsigned int*)alloc((size_t)E * 4);
  unsigned short* ssrc = (unsigned short*)alloc((size_t)E * 2);

  const int gEdge = (E + CHUNK - 1) / CHUNK;
  const int gGather = (N + 3) / 4;
  const int gMlp = (N + 127) / 128;

  // CSR build
  hipMemsetAsync(bucketCount, 0, NBMAX * 4, stream);
  s1_hist<<<gEdge, 256, 0, stream>>>(dst, bucketCount, E);
  s2_scan<<<1, 256, 0, stream>>>(bucketCount, bucketOff, gCursor, rs, NB, N, E);
  s3_scatter<<<gEdge, 256, 0, stream>>>(src, dst, gCursor, bucketed, E, NB);
  s4_fill<<<NB, 256, 0, stream>>>(bucketed, bucketOff, rs, ssrc, N);

  // weight prep + x -> bf16
  prep_w<<<(3 * 2 * 16384 + 255) / 256, 256, 0, stream>>>(W1, W2, wt);
  conv_bf16<<<(N * 64 + 255) / 256, 256, 0, stream>>>(x, hb, N * 64);

  auto WT = [&](int layer, int mat) { return wt + ((size_t)(layer * 2 + mat)) * 2 * 16384; };

  // layer 0
  gather_zb<<<gGather, 256, 0, stream>>>(hb, rs, ssrc, zb, N);
  mlp_mfma<<<gMlp, 256, 0, stream>>>(zb, WT(0, 0), WT(0, 1), b1, b2,
                                     nullptr, (unsigned short*)hb, N);
  // layer 1
  gather_zb<<<gGather, 256, 0, stream>>>(hb, rs, ssrc, zb, N);
  mlp_mfma<<<gMlp, 256, 0, stream>>>(zb, WT(1, 0), WT(1, 1), b1 + DD, b2 + DD,
                                     nullptr, (unsigned short*)hb, N);
  // layer 2 -> f32 output
  gather_zb<<<gGather, 256, 0, stream>>>(hb, rs, ssrc, zb, N);
  mlp_mfma<<<gMlp, 256, 0, stream>>>(zb, WT(2, 0), WT(2, 1), b1 + 2 * DD, b2 + 2 * DD,
                                     h_final, nullptr, N);

  classifier_k<<<(N * 16 + 255) / 256, 256, 0, stream>>>(h_final, Wc, bc, logits, N);
}